// Round 5
// baseline (440.055 us; speedup 1.0000x reference)
//
#include <hip/hip_runtime.h>
#include <hip/hip_cooperative_groups.h>
#include <math.h>

namespace cg = cooperative_groups;

#define NSAMP 32768   // 2^15 = 512 * 64
#define NDEL  512
#define NFR   16
#define BATCH 8
#define TWO_PI 6.283185307179586f

__device__ __forceinline__ float2 cmul(float2 a, float2 b) {
    return make_float2(a.x*b.x - a.y*b.y, a.x*b.y + a.y*b.x);
}
__device__ __forceinline__ float2 cadd(float2 a, float2 b){ return make_float2(a.x+b.x, a.y+b.y); }
__device__ __forceinline__ float2 csub(float2 a, float2 b){ return make_float2(a.x-b.x, a.y-b.y); }
// multiply by sign*i : fwd(sign=-1) -> -i*z = (y,-x) ; inv(+1) -> +i*z = (-y,x)
__device__ __forceinline__ float2 crot(float2 z, float sign){ return make_float2(-sign*z.y, sign*z.x); }

// LDS index swizzle to break power-of-2 strides (i -> i + i/8)
__device__ __forceinline__ int phi(int i){ return i + (i >> 3); }

__device__ __forceinline__ void bfly8(const float2 v[8], float sign, float2 X[8]) {
    const float S2 = 0.70710678118654752f;
    float2 t0 = cadd(v[0], v[4]), t1 = csub(v[0], v[4]);
    float2 t2 = cadd(v[2], v[6]), t3 = crot(csub(v[2], v[6]), sign);
    float2 E0 = cadd(t0, t2), E1 = cadd(t1, t3), E2 = csub(t0, t2), E3 = csub(t1, t3);
    float2 u0 = cadd(v[1], v[5]), u1 = csub(v[1], v[5]);
    float2 u2 = cadd(v[3], v[7]), u3 = crot(csub(v[3], v[7]), sign);
    float2 O0 = cadd(u0, u2), O1 = cadd(u1, u3), O2 = csub(u0, u2), O3 = csub(u1, u3);
    float2 c1 = make_float2( S2, sign*S2);
    float2 c3 = make_float2(-S2, sign*S2);
    float2 w1o = cmul(c1, O1);
    float2 w2o = crot(O2, sign);
    float2 w3o = cmul(c3, O3);
    X[0]=cadd(E0,O0);  X[4]=csub(E0,O0);
    X[1]=cadd(E1,w1o); X[5]=csub(E1,w1o);
    X[2]=cadd(E2,w2o); X[6]=csub(E2,w2o);
    X[3]=cadd(E3,w3o); X[7]=csub(E3,w3o);
}

__device__ __forceinline__ void twiddle_q(float2 v[8], float ang1) {
    float sa, ca; __sincosf(ang1, &sa, &ca);
    float2 w1 = make_float2(ca, sa), wq = w1;
#pragma unroll
    for (int q = 1; q < 8; ++q) { v[q] = cmul(v[q], wq); wq = cmul(wq, w1); }
}

// ---------------------------------------------------------------------------
// Phase 1: fused softmax + damping + divisor-sieve + impulse/noise build.
// task = (b, f, quarter): 512-sample window. Output written TRANSPOSED:
// A_T[b][n2][n1], n = 64*n1 + n2 (thread t = n2 writes 8 consecutive complex).
__device__ void phase_build(int task, const float* __restrict__ impulse,
                            const float* __restrict__ dsel,
                            const float* __restrict__ damping,
                            const float* __restrict__ noise,
                            float2* __restrict__ At, float2* sbuf) {
    const int b   = task >> 6;
    const int f   = (task >> 2) & 15;
    const int sub = task & 3;
    const int tid = threadIdx.x;                 // 64 threads
    float* Wrow = (float*)sbuf;                  // [512]
    float* dl   = Wrow + 512;                    // [512]
    float* red  = dl + 512;                      // [64]  (total 1088 floats <= 2304)

    float v[8], m = -1e30f;
#pragma unroll
    for (int k = 0; k < 8; ++k) {
        v[k] = dsel[(b*NDEL + tid + 64*k)*NFR + f];
        m = fmaxf(m, v[k]);
    }
    red[tid] = m;
    __syncthreads();
    for (int off = 32; off > 0; off >>= 1) {
        if (tid < off) red[tid] = fmaxf(red[tid], red[tid+off]);
        __syncthreads();
    }
    float M = red[0];
    __syncthreads();
    float e[8], s = 0.0f;
#pragma unroll
    for (int k = 0; k < 8; ++k) { e[k] = expf(v[k] - M); s += e[k]; }
    red[tid] = s;
    __syncthreads();
    for (int off = 32; off > 0; off >>= 1) {
        if (tid < off) red[tid] += red[tid+off];
        __syncthreads();
    }
    float S = red[0];
    float damp = 1.0f/(1.0f + expf(-damping[b])) * 0.9999f;
    float scale = damp / S;
#pragma unroll
    for (int k = 0; k < 8; ++k) Wrow[tid + 64*k] = e[k] * scale;
    for (int k = tid; k < 512; k += 64) dl[k] = 0.0f;
    __syncthreads();

    const unsigned start = ((unsigned)f << 11) + ((unsigned)sub << 9);
    const float fstart = (float)start;

    // Phase A: small t (1..63), block-uniform t, lanes over multiples
    for (unsigned t = 1; t < 64; ++t) {
        float wt = Wrow[t-1];
        unsigned q0 = (unsigned)(__fdividef(fstart, (float)t));
        unsigned n0 = q0 * t;
        while (n0 < start) n0 += t;
        while (n0 >= start + t) n0 -= t;
        for (unsigned i = (n0 - start) + (unsigned)tid * t; i < 512u; i += 64u * t)
            atomicAdd(&dl[i], wt);
    }
    // Phase B: large t (64..512), lane-parallel over t
    for (unsigned t = 64u + (unsigned)tid; t <= 512u; t += 64u) {
        float wt = Wrow[t-1];
        unsigned q0 = (unsigned)(__fdividef(fstart, (float)t));
        unsigned n0 = q0 * t;
        while (n0 < start) n0 += t;
        while (n0 >= start + t) n0 -= t;
        for (unsigned i = n0 - start; i < 512u; i += t)
            atomicAdd(&dl[i], wt);
    }
    __syncthreads();

    // epilogue: impulse^2 linear interp * noise; thread t = n2 writes 8
    // consecutive n1 slots of the transposed layout
    const int n1base = (int)(start >> 6);        // f*32 + sub*8
    float2* op = At + b*NSAMP + tid*512 + n1base;
#pragma unroll
    for (int q = 0; q < 8; ++q) {
        int n = (int)start + tid + 64*q;
        float pos = (n + 0.5f) * (1.0f/256.0f) - 0.5f;
        pos = fminf(fmaxf(pos, 0.0f), 127.0f);
        int i0 = (int)pos;
        float w = pos - (float)i0;
        int i1 = (i0 + 1 > 127) ? 127 : i0 + 1;
        float x0 = impulse[b*128 + i0]; x0 *= x0;
        float x1 = impulse[b*128 + i1]; x1 *= x1;
        float iv = (x0*(1.0f - w) + x1*w) * noise[b*NSAMP + n];
        op[q] = make_float2(dl[tid + 64*q], iv);
    }
}

// ---------------------------------------------------------------------------
// Phase 2/4: 512-pt FFT over n1 for (s, n2). Input transposed src_T[n2*512+n1]
// (coalesced). Three radix-8 Stockham stages through LDS; four-step twiddle
// w_N^{n2*k1}; store [n2*512 + k1]. If filt != nullptr: Hermitian unpack of
// Z = FFT(d + i*imp) (partner at row (64-n2)&63, reverse-contiguous col),
// filter envelope multiply, combined ortho scale.
__device__ void phase_fft512(int task, const float2* __restrict__ src,
                             float2* __restrict__ dst,
                             const float* __restrict__ filt,
                             float sign, float2* sbuf, float* fs) {
    const int j  = threadIdx.x;          // 64
    const int s  = task >> 6;
    const int n2 = task & 63;
    float2* buf0 = sbuf;                 // [576]
    float2* buf1 = sbuf + 576;           // [576]
    if (filt && j < NFR)
        fs[j] = 1.0f/(1.0f + expf(-filt[s*NFR + j]));
    __syncthreads();

    const float2* sp = src + s * NSAMP;
    float2 v[8], X[8];
    if (!filt) {
#pragma unroll
        for (int q = 0; q < 8; ++q) v[q] = sp[n2*512 + j + 64*q];
    } else {
        const float SCALE = 1.0f / (32768.0f * 181.01933598375618f); // N^{-3/2}
        const int prow = (64 - n2) & 63;
#pragma unroll
        for (int q = 0; q < 8; ++q) {
            int n1 = j + 64*q;
            int m  = 64*n1 + n2;                     // natural bin index
            float2 Zk = sp[n2*512 + n1];
            int pcol = n2 ? (511 - n1) : ((512 - n1) & 511);
            float2 Zr = sp[prow*512 + pcol];         // Z[N-m]
            float2 Zrc = make_float2(Zr.x, -Zr.y);
            float2 D = make_float2(0.5f*(Zk.x + Zrc.x), 0.5f*(Zk.y + Zrc.y));
            float2 df = make_float2(Zk.x - Zrc.x, Zk.y - Zrc.y);
            float2 I = make_float2(0.5f*df.y, -0.5f*df.x);
            int jjb = (m <= NSAMP - m) ? m : NSAMP - m;
            float fv = 0.0f;
            if (jjb < NSAMP/2) {
                float pos = (jjb + 0.5f) * (1.0f/1024.0f) - 0.5f;
                pos = fminf(fmaxf(pos, 0.0f), 15.0f);
                int i0 = (int)pos;
                float w = pos - (float)i0;
                int i1 = (i0 + 1 > 15) ? 15 : i0 + 1;
                fv = fs[i0]*(1.0f - w) + fs[i1]*w;
            }
            float2 spc = cmul(D, I);
            float g = fv * SCALE;
            v[q] = make_float2(spc.x * g, spc.y * g);
        }
    }

    // stage 1 (lNs=0)
    bfly8(v, sign, X);
#pragma unroll
    for (int r = 0; r < 8; ++r) buf0[phi(8*j + r)] = X[r];
    __syncthreads();
    // stage 2 (lNs=3)
#pragma unroll
    for (int q = 0; q < 8; ++q) v[q] = buf0[phi(j + 64*q)];
    int jm = j & 7;
    twiddle_q(v, sign * TWO_PI * (float)jm * (1.0f/64.0f));
    bfly8(v, sign, X);
#pragma unroll
    for (int r = 0; r < 8; ++r) buf1[phi(((j>>3)<<6) + jm + (r<<3))] = X[r];
    __syncthreads();
    // stage 3 (lNs=6) -> natural order k1 = j + 64r
#pragma unroll
    for (int q = 0; q < 8; ++q) v[q] = buf1[phi(j + 64*q)];
    twiddle_q(v, sign * TWO_PI * (float)j * (1.0f/512.0f));
    bfly8(v, sign, X);

    // four-step twiddle w_N^{n2*k1}, store G[n2*512 + k1] (coalesced)
    float2* dp = dst + s * NSAMP + n2 * 512;
#pragma unroll
    for (int r = 0; r < 8; ++r) {
        int k1 = j + 64*r;
        int pr = (n2 * k1) & (NSAMP - 1);
        float sa, ca; __sincosf(sign * TWO_PI * (float)pr * (1.0f/32768.0f), &sa, &ca);
        dp[k1] = cmul(X[r], make_float2(ca, sa));
    }
}

// ---------------------------------------------------------------------------
// Phase 3/5: 64-pt FFT over n2 for each k1 (two radix-8 stages); 8 sub-FFTs
// per wave (lane = c + 8*jj). If dstT != nullptr (forward): store Z transposed
// Z_T[k&63][k>>6 + 8*k2]. If out_real != nullptr: store Re() natural order.
__device__ void phase_fft64(int task, const float2* __restrict__ src,
                            float2* __restrict__ dstT,
                            float* __restrict__ out_real,
                            float sign, float2* sbuf) {
    const int l = threadIdx.x;           // 64
    const int c = l & 7, jj = l >> 3;
    const int s = task >> 6;
    const int k1base = (task & 63) << 3;
    float2* buf = sbuf;                  // [576]

    const float2* sp = src + s * NSAMP;
    float2 v[8], X[8];
#pragma unroll
    for (int q = 0; q < 8; ++q) v[q] = sp[(jj + 8*q)*512 + k1base + c];

    // stage 1 (lNs=0)
    bfly8(v, sign, X);
#pragma unroll
    for (int r = 0; r < 8; ++r) buf[phi(c*64 + jj*8 + r)] = X[r];
    __syncthreads();
    // stage 2 (lNs=3) -> k2 = jj + 8r
#pragma unroll
    for (int q = 0; q < 8; ++q) v[q] = buf[phi(c*64 + jj + 8*q)];
    twiddle_q(v, sign * TWO_PI * (float)jj * (1.0f/64.0f));
    bfly8(v, sign, X);

    const int k1 = k1base + c;
    if (out_real) {
        float* op = out_real + s * NSAMP + k1;
#pragma unroll
        for (int r = 0; r < 8; ++r) op[512*(jj + 8*r)] = X[r].x;
    } else {
        float2* dp = dstT + s * NSAMP + (k1 & 63)*512 + (k1 >> 6) + 8*jj;
#pragma unroll
        for (int r = 0; r < 8; ++r) dp[64*r] = X[r];
    }
}

// ---------------------------------------------------------------------------
// One cooperative kernel: 512 blocks x 64 threads (2 wave-blocks/CU, ~9.3 KB
// LDS each — co-residency guaranteed by hipLaunchCooperativeKernel).
__global__ void __launch_bounds__(64)
fused_kernel(const float* __restrict__ impulse, const float* __restrict__ dsel,
             const float* __restrict__ damping, const float* __restrict__ filt,
             const float* __restrict__ noise, float2* __restrict__ A,
             float2* __restrict__ B, float* __restrict__ out) {
    cg::grid_group grid = cg::this_grid();
    __shared__ float2 sbuf[1152];        // 9216 B, aliased per phase
    __shared__ float  sfs[NFR];
    const int task = blockIdx.x;

    phase_build(task, impulse, dsel, damping, noise, A, sbuf);
    __threadfence(); grid.sync();
    phase_fft512(task, A, B, nullptr, -1.0f, sbuf, sfs);
    __threadfence(); grid.sync();
    phase_fft64(task, B, A, nullptr, -1.0f, sbuf);
    __threadfence(); grid.sync();
    phase_fft512(task, A, B, filt, 1.0f, sbuf, sfs);
    __threadfence(); grid.sync();
    phase_fft64(task, B, nullptr, out, 1.0f, sbuf);
}

// ---------------------------------------------------------------------------
extern "C" void kernel_launch(void* const* d_in, const int* in_sizes, int n_in,
                              void* d_out, int out_size, void* d_ws, size_t ws_size,
                              hipStream_t stream) {
    const float* impulse = (const float*)d_in[0];   // [8,128]
    const float* dsel    = (const float*)d_in[1];   // [8,512,16]
    const float* damping = (const float*)d_in[2];   // [8,1]
    const float* filt    = (const float*)d_in[3];   // [8,16]
    const float* noise   = (const float*)d_in[4];   // [8,1,32768]
    // d_in[5] (delays, 64 MB): pure structure delays[i,n] = ((i+1) | n) — never read.
    float* out = (float*)d_out;                     // [8,32768]

    float2* A = (float2*)d_ws;                      // 2 MB
    float2* B = A + BATCH * NSAMP;                  // 2 MB

    void* args[] = {(void*)&impulse, (void*)&dsel, (void*)&damping, (void*)&filt,
                    (void*)&noise,   (void*)&A,    (void*)&B,       (void*)&out};
    hipLaunchCooperativeKernel((const void*)fused_kernel, dim3(512), dim3(64),
                               args, 0, stream);
}

// Round 6
// 134.886 us; speedup vs baseline: 3.2624x; 3.2624x over previous
//
#include <hip/hip_runtime.h>
#include <math.h>

#define NSAMP 32768   // 2^15 = 512 * 64
#define NDEL  512
#define NFR   16
#define BATCH 8
#define TWO_PI 6.283185307179586f

__device__ __forceinline__ float2 cmul(float2 a, float2 b) {
    return make_float2(a.x*b.x - a.y*b.y, a.x*b.y + a.y*b.x);
}
__device__ __forceinline__ float2 cadd(float2 a, float2 b){ return make_float2(a.x+b.x, a.y+b.y); }
__device__ __forceinline__ float2 csub(float2 a, float2 b){ return make_float2(a.x-b.x, a.y-b.y); }
// multiply by sign*i : fwd(sign=-1) -> -i*z = (y,-x) ; inv(+1) -> +i*z = (-y,x)
__device__ __forceinline__ float2 crot(float2 z, float sign){ return make_float2(-sign*z.y, sign*z.x); }

// LDS index swizzle to break power-of-2 strides (i -> i + i/8)
__device__ __forceinline__ int phi(int i){ return i + (i >> 3); }

__device__ __forceinline__ void bfly8(const float2 v[8], float sign, float2 X[8]) {
    const float S2 = 0.70710678118654752f;
    float2 t0 = cadd(v[0], v[4]), t1 = csub(v[0], v[4]);
    float2 t2 = cadd(v[2], v[6]), t3 = crot(csub(v[2], v[6]), sign);
    float2 E0 = cadd(t0, t2), E1 = cadd(t1, t3), E2 = csub(t0, t2), E3 = csub(t1, t3);
    float2 u0 = cadd(v[1], v[5]), u1 = csub(v[1], v[5]);
    float2 u2 = cadd(v[3], v[7]), u3 = crot(csub(v[3], v[7]), sign);
    float2 O0 = cadd(u0, u2), O1 = cadd(u1, u3), O2 = csub(u0, u2), O3 = csub(u1, u3);
    float2 c1 = make_float2( S2, sign*S2);
    float2 c3 = make_float2(-S2, sign*S2);
    float2 w1o = cmul(c1, O1);
    float2 w2o = crot(O2, sign);
    float2 w3o = cmul(c3, O3);
    X[0]=cadd(E0,O0);  X[4]=csub(E0,O0);
    X[1]=cadd(E1,w1o); X[5]=csub(E1,w1o);
    X[2]=cadd(E2,w2o); X[6]=csub(E2,w2o);
    X[3]=cadd(E3,w3o); X[7]=csub(E3,w3o);
}

__device__ __forceinline__ void twiddle_q(float2 v[8], float ang1) {
    float sa, ca; __sincosf(ang1, &sa, &ca);
    float2 w1 = make_float2(ca, sa), wq = w1;
#pragma unroll
    for (int q = 1; q < 8; ++q) { v[q] = cmul(v[q], wq); wq = cmul(wq, w1); }
}

// ---------------------------------------------------------------------------
// Fused softmax + damping + divisor-sieve + impulse/noise build.
// One wave-block per (b, f, quarter): 512-sample window. d[n] = sum_{t|n,
// t<=512} W[t-1] sieved into LDS. Output written TRANSPOSED:
// A_T[b][n2][n1] with n = 64*n1 + n2 -> thread t (= n2) writes 8 consecutive
// complex (64 B contiguous), so the fft512 consumer loads coalesced.
__global__ void build_kernel(const float* __restrict__ impulse,
                             const float* __restrict__ dsel,
                             const float* __restrict__ damping,
                             const float* __restrict__ noise,
                             float2* __restrict__ At) {
    const int b   = blockIdx.x >> 6;
    const int f   = (blockIdx.x >> 2) & 15;
    const int sub = blockIdx.x & 3;
    const int tid = threadIdx.x;                 // 64 threads
    __shared__ float Wrow[NDEL];
    __shared__ float dl[512];
    __shared__ float red[64];

    // --- softmax over 512 delay logits for this (b,f), damping folded in ---
    float v[8], m = -1e30f;
#pragma unroll
    for (int k = 0; k < 8; ++k) {
        v[k] = dsel[(b*NDEL + tid + 64*k)*NFR + f];
        m = fmaxf(m, v[k]);
    }
    red[tid] = m;
    __syncthreads();
    for (int off = 32; off > 0; off >>= 1) {
        if (tid < off) red[tid] = fmaxf(red[tid], red[tid+off]);
        __syncthreads();
    }
    float M = red[0];
    __syncthreads();
    float e[8], s = 0.0f;
#pragma unroll
    for (int k = 0; k < 8; ++k) { e[k] = expf(v[k] - M); s += e[k]; }
    red[tid] = s;
    __syncthreads();
    for (int off = 32; off > 0; off >>= 1) {
        if (tid < off) red[tid] += red[tid+off];
        __syncthreads();
    }
    float S = red[0];
    float damp = 1.0f/(1.0f + expf(-damping[b])) * 0.9999f;
    float scale = damp / S;
#pragma unroll
    for (int k = 0; k < 8; ++k) Wrow[tid + 64*k] = e[k] * scale;
    for (int k = tid; k < 512; k += 64) dl[k] = 0.0f;
    __syncthreads();

    const unsigned start = ((unsigned)f << 11) + ((unsigned)sub << 9);
    const float fstart = (float)start;

    // --- Phase A: small t (1..63), block-uniform t, lanes over multiples ---
    for (unsigned t = 1; t < 64; ++t) {
        float wt = Wrow[t-1];
        unsigned q0 = (unsigned)(__fdividef(fstart, (float)t));
        unsigned n0 = q0 * t;
        while (n0 < start) n0 += t;
        while (n0 >= start + t) n0 -= t;
        for (unsigned i = (n0 - start) + (unsigned)tid * t; i < 512u; i += 64u * t)
            atomicAdd(&dl[i], wt);
    }
    // --- Phase B: large t (64..512), lane-parallel over t ---
    for (unsigned t = 64u + (unsigned)tid; t <= 512u; t += 64u) {
        float wt = Wrow[t-1];
        unsigned q0 = (unsigned)(__fdividef(fstart, (float)t));
        unsigned n0 = q0 * t;
        while (n0 < start) n0 += t;
        while (n0 >= start + t) n0 -= t;
        for (unsigned i = n0 - start; i < 512u; i += t)
            atomicAdd(&dl[i], wt);
    }
    __syncthreads();

    // --- epilogue: impulse^2 linear interp * noise; thread t = n2, writes
    //     8 consecutive n1 slots of the transposed layout ---
    const int n1base = (int)(start >> 6);        // f*32 + sub*8
    float2* op = At + b*NSAMP + tid*512 + n1base;
#pragma unroll
    for (int q = 0; q < 8; ++q) {
        int n = (int)start + tid + 64*q;
        float pos = (n + 0.5f) * (1.0f/256.0f) - 0.5f;
        pos = fminf(fmaxf(pos, 0.0f), 127.0f);
        int i0 = (int)pos;
        float w = pos - (float)i0;
        int i1 = (i0 + 1 > 127) ? 127 : i0 + 1;
        float x0 = impulse[b*128 + i0]; x0 *= x0;
        float x1 = impulse[b*128 + i1]; x1 *= x1;
        float iv = (x0*(1.0f - w) + x1*w) * noise[b*NSAMP + n];
        op[q] = make_float2(dl[tid + 64*q], iv);
    }
}

// ---------------------------------------------------------------------------
// Four-step FFT, N = 32768 = 512*64, n = n1*64 + n2, k = k1 + 512*k2.
// Kernel 1: one wave-block per (s, n2) -> 512 blocks x 64 threads. INPUT IS
// TRANSPOSED: src_T[n2*512 + n1] -> loads fully coalesced. Three radix-8
// Stockham stages through LDS; apply twiddle w_N^{n2*k1}; store [n2*512+k1].
// If filt != nullptr (first inverse kernel): load phase does the Hermitian
// unpack of Z = FFT(d + i*imp) (partner bin N-m lives at row (64-n2)&63,
// col 511-n1 — also coalesced), filter multiply, and the ortho scale.
__global__ void fft512_kernel(const float2* __restrict__ src,
                              float2* __restrict__ dst,
                              const float* __restrict__ filt,
                              float sign) {
    const int j  = threadIdx.x;          // 64
    const int s  = blockIdx.x >> 6;
    const int n2 = blockIdx.x & 63;
    __shared__ float2 buf[2][576];
    __shared__ float fs[NFR];
    if (filt && j < NFR)
        fs[j] = 1.0f/(1.0f + expf(-filt[s*NFR + j]));
    __syncthreads();

    const float2* sp = src + s * NSAMP;
    float2 v[8], X[8];
    if (!filt) {
#pragma unroll
        for (int q = 0; q < 8; ++q) v[q] = sp[n2*512 + j + 64*q];
    } else {
        const float SCALE = 1.0f / (32768.0f * 181.01933598375618f); // N^{-3/2}
        const int prow = (64 - n2) & 63;
#pragma unroll
        for (int q = 0; q < 8; ++q) {
            int n1 = j + 64*q;
            int m  = 64*n1 + n2;                     // natural bin index
            float2 Zk = sp[n2*512 + n1];
            int pcol = n2 ? (511 - n1) : ((512 - n1) & 511);
            float2 Zr = sp[prow*512 + pcol];         // Z[N-m]
            float2 Zrc = make_float2(Zr.x, -Zr.y);
            float2 D = make_float2(0.5f*(Zk.x + Zrc.x), 0.5f*(Zk.y + Zrc.y));
            float2 df = make_float2(Zk.x - Zrc.x, Zk.y - Zrc.y);
            float2 I = make_float2(0.5f*df.y, -0.5f*df.x);
            int jjb = (m <= NSAMP - m) ? m : NSAMP - m;
            float fv = 0.0f;
            if (jjb < NSAMP/2) {
                float pos = (jjb + 0.5f) * (1.0f/1024.0f) - 0.5f;
                pos = fminf(fmaxf(pos, 0.0f), 15.0f);
                int i0 = (int)pos;
                float w = pos - (float)i0;
                int i1 = (i0 + 1 > 15) ? 15 : i0 + 1;
                fv = fs[i0]*(1.0f - w) + fs[i1]*w;
            }
            float2 spc = cmul(D, I);
            float g = fv * SCALE;
            v[q] = make_float2(spc.x * g, spc.y * g);
        }
    }

    // stage 1 (lNs=0)
    bfly8(v, sign, X);
#pragma unroll
    for (int r = 0; r < 8; ++r) buf[0][phi(8*j + r)] = X[r];
    __syncthreads();
    // stage 2 (lNs=3)
#pragma unroll
    for (int q = 0; q < 8; ++q) v[q] = buf[0][phi(j + 64*q)];
    int jm = j & 7;
    twiddle_q(v, sign * TWO_PI * (float)jm * (1.0f/64.0f));
    bfly8(v, sign, X);
#pragma unroll
    for (int r = 0; r < 8; ++r) buf[1][phi(((j>>3)<<6) + jm + (r<<3))] = X[r];
    __syncthreads();
    // stage 3 (lNs=6) -> natural order k1 = j + 64r
#pragma unroll
    for (int q = 0; q < 8; ++q) v[q] = buf[1][phi(j + 64*q)];
    twiddle_q(v, sign * TWO_PI * (float)j * (1.0f/512.0f));
    bfly8(v, sign, X);

    // four-step twiddle w_N^{n2*k1}, store G[n2*512 + k1] (coalesced)
    float2* dp = dst + s * NSAMP + n2 * 512;
#pragma unroll
    for (int r = 0; r < 8; ++r) {
        int k1 = j + 64*r;
        int pr = (n2 * k1) & (NSAMP - 1);
        float sa, ca; __sincosf(sign * TWO_PI * (float)pr * (1.0f/32768.0f), &sa, &ca);
        dp[k1] = cmul(X[r], make_float2(ca, sa));
    }
}

// ---------------------------------------------------------------------------
// Kernel 2: 64-pt FFT over n2 for each k1 (two radix-8 stages). One wave-block
// handles 8 sub-FFTs: lane = c + 8*jj. Grid: 512 blocks x 64 threads.
// If dstT != nullptr (forward): store Z TRANSPOSED for the inverse fft512:
//   Z_T[k&63][k>>6] with k = k1 + 512*k2 (scattered 8B stores, absorbed by L2).
// If out_real != nullptr (last inverse stage): store Re() in natural order.
__global__ void fft64_kernel(const float2* __restrict__ src,
                             float2* __restrict__ dstT,
                             float* __restrict__ out_real,
                             float sign) {
    const int l = threadIdx.x;           // 64
    const int c = l & 7, jj = l >> 3;
    const int s = blockIdx.x >> 6;
    const int k1base = (blockIdx.x & 63) << 3;
    __shared__ float2 buf[576];

    const float2* sp = src + s * NSAMP;
    float2 v[8], X[8];
#pragma unroll
    for (int q = 0; q < 8; ++q) v[q] = sp[(jj + 8*q)*512 + k1base + c];

    // stage 1 (lNs=0)
    bfly8(v, sign, X);
#pragma unroll
    for (int r = 0; r < 8; ++r) buf[phi(c*64 + jj*8 + r)] = X[r];
    __syncthreads();
    // stage 2 (lNs=3) -> k2 = jj + 8r
#pragma unroll
    for (int q = 0; q < 8; ++q) v[q] = buf[phi(c*64 + jj + 8*q)];
    twiddle_q(v, sign * TWO_PI * (float)jj * (1.0f/64.0f));
    bfly8(v, sign, X);

    const int k1 = k1base + c;
    if (out_real) {
        float* op = out_real + s * NSAMP + k1;
#pragma unroll
        for (int r = 0; r < 8; ++r) op[512*(jj + 8*r)] = X[r].x;
    } else {
        // transposed: row = k1&63, col = (k1>>6) + 8*k2, k2 = jj + 8r
        float2* dp = dstT + s * NSAMP + (k1 & 63)*512 + (k1 >> 6) + 8*jj;
#pragma unroll
        for (int r = 0; r < 8; ++r) dp[64*r] = X[r];
    }
}

// ---------------------------------------------------------------------------
extern "C" void kernel_launch(void* const* d_in, const int* in_sizes, int n_in,
                              void* d_out, int out_size, void* d_ws, size_t ws_size,
                              hipStream_t stream) {
    const float* impulse = (const float*)d_in[0];   // [8,128]
    const float* dsel    = (const float*)d_in[1];   // [8,512,16]
    const float* damping = (const float*)d_in[2];   // [8,1]
    const float* filt    = (const float*)d_in[3];   // [8,16]
    const float* noise   = (const float*)d_in[4];   // [8,1,32768]
    // d_in[5] (delays, 64 MB): pure structure delays[i,n] = ((i+1) | n) — never read.
    float* out = (float*)d_out;                     // [8,32768]

    float2* A = (float2*)d_ws;                      // 2 MB
    float2* B = A + BATCH * NSAMP;                  // 2 MB

    // NOTE (R5 lesson): do NOT fuse these via hipLaunchCooperativeKernel —
    // grid.sync() on gfx950 costs ~75 µs/barrier (cross-XCD L2 flush + spin),
    // 25x more than a stream-ordered kernel boundary. 5 kernels is optimal.
    build_kernel<<<dim3(512), dim3(64), 0, stream>>>(impulse, dsel, damping, noise, A);
    // forward FFT: fft512 reads A_T coalesced; fft64 stores Z transposed into A
    fft512_kernel<<<dim3(512), dim3(64), 0, stream>>>(A, B, nullptr, -1.0f);
    fft64_kernel <<<dim3(512), dim3(64), 0, stream>>>(B, A, nullptr, -1.0f);
    // inverse FFT with pointwise fused; reads Z_T coalesced (both bins m, N-m)
    fft512_kernel<<<dim3(512), dim3(64), 0, stream>>>(A, B, filt, 1.0f);
    fft64_kernel <<<dim3(512), dim3(64), 0, stream>>>(B, nullptr, out, 1.0f);
}

// Round 7
// 133.859 us; speedup vs baseline: 3.2875x; 1.0077x over previous
//
#include <hip/hip_runtime.h>
#include <math.h>

#define NSAMP 32768   // 2^15 = 512 * 64
#define NDEL  512
#define NFR   16
#define BATCH 8
#define TWO_PI 6.283185307179586f

__device__ __forceinline__ float2 cmul(float2 a, float2 b) {
    return make_float2(a.x*b.x - a.y*b.y, a.x*b.y + a.y*b.x);
}
__device__ __forceinline__ float2 cadd(float2 a, float2 b){ return make_float2(a.x+b.x, a.y+b.y); }
__device__ __forceinline__ float2 csub(float2 a, float2 b){ return make_float2(a.x-b.x, a.y-b.y); }
// multiply by sign*i : fwd(sign=-1) -> -i*z = (y,-x) ; inv(+1) -> +i*z = (-y,x)
__device__ __forceinline__ float2 crot(float2 z, float sign){ return make_float2(-sign*z.y, sign*z.x); }

// LDS index swizzle to break power-of-2 strides (i -> i + i/8)
__device__ __forceinline__ int phi(int i){ return i + (i >> 3); }

__device__ __forceinline__ void bfly8(const float2 v[8], float sign, float2 X[8]) {
    const float S2 = 0.70710678118654752f;
    float2 t0 = cadd(v[0], v[4]), t1 = csub(v[0], v[4]);
    float2 t2 = cadd(v[2], v[6]), t3 = crot(csub(v[2], v[6]), sign);
    float2 E0 = cadd(t0, t2), E1 = cadd(t1, t3), E2 = csub(t0, t2), E3 = csub(t1, t3);
    float2 u0 = cadd(v[1], v[5]), u1 = csub(v[1], v[5]);
    float2 u2 = cadd(v[3], v[7]), u3 = crot(csub(v[3], v[7]), sign);
    float2 O0 = cadd(u0, u2), O1 = cadd(u1, u3), O2 = csub(u0, u2), O3 = csub(u1, u3);
    float2 c1 = make_float2( S2, sign*S2);
    float2 c3 = make_float2(-S2, sign*S2);
    float2 w1o = cmul(c1, O1);
    float2 w2o = crot(O2, sign);
    float2 w3o = cmul(c3, O3);
    X[0]=cadd(E0,O0);  X[4]=csub(E0,O0);
    X[1]=cadd(E1,w1o); X[5]=csub(E1,w1o);
    X[2]=cadd(E2,w2o); X[6]=csub(E2,w2o);
    X[3]=cadd(E3,w3o); X[7]=csub(E3,w3o);
}

__device__ __forceinline__ void twiddle_q(float2 v[8], float ang1) {
    float sa, ca; __sincosf(ang1, &sa, &ca);
    float2 w1 = make_float2(ca, sa), wq = w1;
#pragma unroll
    for (int q = 1; q < 8; ++q) { v[q] = cmul(v[q], wq); wq = cmul(wq, w1); }
}

// ---------------------------------------------------------------------------
// Kernel 1: fused softmax + damping + divisor-sieve + impulse/noise build.
// One wave-block per (b, f, quarter): 512-sample window. Output TRANSPOSED:
// A_T[b][n2][n1] with n = 64*n1 + n2 (thread t = n2 writes 8 consecutive).
__global__ void build_kernel(const float* __restrict__ impulse,
                             const float* __restrict__ dsel,
                             const float* __restrict__ damping,
                             const float* __restrict__ noise,
                             float2* __restrict__ At) {
    const int b   = blockIdx.x >> 6;
    const int f   = (blockIdx.x >> 2) & 15;
    const int sub = blockIdx.x & 3;
    const int tid = threadIdx.x;                 // 64 threads
    __shared__ float Wrow[NDEL];
    __shared__ float dl[512];
    __shared__ float red[64];

    float v[8], m = -1e30f;
#pragma unroll
    for (int k = 0; k < 8; ++k) {
        v[k] = dsel[(b*NDEL + tid + 64*k)*NFR + f];
        m = fmaxf(m, v[k]);
    }
    red[tid] = m;
    __syncthreads();
    for (int off = 32; off > 0; off >>= 1) {
        if (tid < off) red[tid] = fmaxf(red[tid], red[tid+off]);
        __syncthreads();
    }
    float M = red[0];
    __syncthreads();
    float e[8], s = 0.0f;
#pragma unroll
    for (int k = 0; k < 8; ++k) { e[k] = expf(v[k] - M); s += e[k]; }
    red[tid] = s;
    __syncthreads();
    for (int off = 32; off > 0; off >>= 1) {
        if (tid < off) red[tid] += red[tid+off];
        __syncthreads();
    }
    float S = red[0];
    float damp = 1.0f/(1.0f + expf(-damping[b])) * 0.9999f;
    float scale = damp / S;
#pragma unroll
    for (int k = 0; k < 8; ++k) Wrow[tid + 64*k] = e[k] * scale;
    for (int k = tid; k < 512; k += 64) dl[k] = 0.0f;
    __syncthreads();

    const unsigned start = ((unsigned)f << 11) + ((unsigned)sub << 9);
    const float fstart = (float)start;

    // small t (1..63): block-uniform t, lanes over multiples
    for (unsigned t = 1; t < 64; ++t) {
        float wt = Wrow[t-1];
        unsigned q0 = (unsigned)(__fdividef(fstart, (float)t));
        unsigned n0 = q0 * t;
        while (n0 < start) n0 += t;
        while (n0 >= start + t) n0 -= t;
        for (unsigned i = (n0 - start) + (unsigned)tid * t; i < 512u; i += 64u * t)
            atomicAdd(&dl[i], wt);
    }
    // large t (64..512): lane-parallel over t
    for (unsigned t = 64u + (unsigned)tid; t <= 512u; t += 64u) {
        float wt = Wrow[t-1];
        unsigned q0 = (unsigned)(__fdividef(fstart, (float)t));
        unsigned n0 = q0 * t;
        while (n0 < start) n0 += t;
        while (n0 >= start + t) n0 -= t;
        for (unsigned i = n0 - start; i < 512u; i += t)
            atomicAdd(&dl[i], wt);
    }
    __syncthreads();

    const int n1base = (int)(start >> 6);        // f*32 + sub*8
    float2* op = At + b*NSAMP + tid*512 + n1base;
#pragma unroll
    for (int q = 0; q < 8; ++q) {
        int n = (int)start + tid + 64*q;
        float pos = (n + 0.5f) * (1.0f/256.0f) - 0.5f;
        pos = fminf(fmaxf(pos, 0.0f), 127.0f);
        int i0 = (int)pos;
        float w = pos - (float)i0;
        int i1 = (i0 + 1 > 127) ? 127 : i0 + 1;
        float x0 = impulse[b*128 + i0]; x0 *= x0;
        float x1 = impulse[b*128 + i1]; x1 *= x1;
        float iv = (x0*(1.0f - w) + x1*w) * noise[b*NSAMP + n];
        op[q] = make_float2(dl[tid + 64*q], iv);
    }
}

// ---------------------------------------------------------------------------
// Kernel 2: forward 512-pt FFT over n1 per (s, n2); input transposed (coalesced),
// three radix-8 Stockham stages through LDS, four-step twiddle w_N^{-n2*k1},
// store G[n2*512 + k1].
__global__ void fft512_fwd_kernel(const float2* __restrict__ src,
                                  float2* __restrict__ dst) {
    const int j  = threadIdx.x;          // 64
    const int s  = blockIdx.x >> 6;
    const int n2 = blockIdx.x & 63;
    __shared__ float2 buf[2][576];
    const float sign = -1.0f;

    const float2* sp = src + s * NSAMP;
    float2 v[8], X[8];
#pragma unroll
    for (int q = 0; q < 8; ++q) v[q] = sp[n2*512 + j + 64*q];

    bfly8(v, sign, X);
#pragma unroll
    for (int r = 0; r < 8; ++r) buf[0][phi(8*j + r)] = X[r];
    __syncthreads();
#pragma unroll
    for (int q = 0; q < 8; ++q) v[q] = buf[0][phi(j + 64*q)];
    int jm = j & 7;
    twiddle_q(v, sign * TWO_PI * (float)jm * (1.0f/64.0f));
    bfly8(v, sign, X);
#pragma unroll
    for (int r = 0; r < 8; ++r) buf[1][phi(((j>>3)<<6) + jm + (r<<3))] = X[r];
    __syncthreads();
#pragma unroll
    for (int q = 0; q < 8; ++q) v[q] = buf[1][phi(j + 64*q)];
    twiddle_q(v, sign * TWO_PI * (float)j * (1.0f/512.0f));
    bfly8(v, sign, X);

    float2* dp = dst + s * NSAMP + n2 * 512;
#pragma unroll
    for (int r = 0; r < 8; ++r) {
        int k1 = j + 64*r;
        int pr = (n2 * k1) & (NSAMP - 1);
        float sa, ca; __sincosf(sign * TWO_PI * (float)pr * (1.0f/32768.0f), &sa, &ca);
        dp[k1] = cmul(X[r], make_float2(ca, sa));
    }
}

// ---------------------------------------------------------------------------
// Kernel 3 (MEGA): per block: 8 spectrum columns = 4 Hermitian pairs.
//   step 1: fwd 64-pt FFT over n2 for each column  -> Z[k1][k2] in LDS
//   step 2: pointwise S = D*I*fv*SCALE in LDS (pair (k, N-k) both in-block;
//           S[N-k] = conj(D*I)*fv*SCALE)
//   step 3: inv 64-pt FFT over k2 per column -> T[k1][n2]; twiddle
//           w_N^{+n2*k1}; store H[n2*512 + k1].
// Columns: group g in [0,64): lows {4g..4g+3}; highs = 512 - low (g=0:
// lows {0..3}, highs {256,511,510,509}; cols 0 and 256 self-paired).
__global__ void mega_kernel(const float2* __restrict__ G,
                            float2* __restrict__ H,
                            const float* __restrict__ filt) {
    const int l  = threadIdx.x;          // 64
    const int cc = l & 7, jj = l >> 3;
    const int s  = blockIdx.x >> 6;
    const int g  = blockIdx.x & 63;
    __shared__ float2 Z[8][65];
    __shared__ float2 buf[576];
    __shared__ float fs[NFR];
    __shared__ int cols[8];

    if (l < NFR) fs[l] = 1.0f/(1.0f + expf(-filt[s*NFR + l]));
    if (l < 8) {
        int col;
        if (l < 4)        col = 4*g + l;
        else if (g == 0)  col = (l == 4) ? 256 : 512 - (l - 4);
        else              col = 512 - 4*g - (l - 4);
        cols[l] = col;
    }
    __syncthreads();

    const float2* sp = G + s * NSAMP;
    const int mycol = cols[cc];
    float2 v[8], X[8];

    // ---- step 1: forward 64-pt FFT (sign=-1) over n2, column mycol ----
#pragma unroll
    for (int q = 0; q < 8; ++q) v[q] = sp[(jj + 8*q)*512 + mycol];
    bfly8(v, -1.0f, X);
#pragma unroll
    for (int r = 0; r < 8; ++r) buf[phi(cc*64 + jj*8 + r)] = X[r];
    __syncthreads();
#pragma unroll
    for (int q = 0; q < 8; ++q) v[q] = buf[phi(cc*64 + jj + 8*q)];
    twiddle_q(v, -TWO_PI * (float)jj * (1.0f/64.0f));
    bfly8(v, -1.0f, X);
#pragma unroll
    for (int r = 0; r < 8; ++r) Z[cc][jj + 8*r] = X[r];   // k2 = jj+8r
    __syncthreads();

    // ---- step 2: pointwise in LDS ----
    const float SCALE = 1.0f / (32768.0f * 181.01933598375618f); // N^{-3/2}
    // general pairs: (c,k2) <-> (c+4, 63-k2), c in [0,4) (skip c==0 when g==0)
#pragma unroll
    for (int it = 0; it < 4; ++it) {
        int c  = l & 3;
        int k2 = (l >> 2) + 16*it;
        if (!(g == 0 && c == 0)) {
            int col = cols[c];
            float2 Zk = Z[c][k2];
            float2 Zr = Z[c+4][63 - k2];
            float2 Zrc = make_float2(Zr.x, -Zr.y);
            float2 D = make_float2(0.5f*(Zk.x + Zrc.x), 0.5f*(Zk.y + Zrc.y));
            float2 df = make_float2(Zk.x - Zrc.x, Zk.y - Zrc.y);
            float2 I = make_float2(0.5f*df.y, -0.5f*df.x);
            int k = col + 512*k2;
            int jjb = (k <= NSAMP - k) ? k : NSAMP - k;
            float fv = 0.0f;
            if (jjb < NSAMP/2) {
                float pos = (jjb + 0.5f) * (1.0f/1024.0f) - 0.5f;
                pos = fminf(fmaxf(pos, 0.0f), 15.0f);
                int i0 = (int)pos;
                float w = pos - (float)i0;
                int i1 = (i0 + 1 > 15) ? 15 : i0 + 1;
                fv = fs[i0]*(1.0f - w) + fs[i1]*w;
            }
            float2 spec = cmul(D, I);
            float gs = fv * SCALE;
            Z[c][k2]        = make_float2( spec.x*gs,  spec.y*gs);
            Z[c+4][63 - k2] = make_float2( spec.x*gs, -spec.y*gs);
        }
    }
    // special self-paired columns for g==0: col 0 (c=0) and col 256 (c=4)
    if (g == 0) {
        if (l <= 32) {            // col 0: k2 <-> (64-k2)&63, k2 in [0,32]
            int k2 = l, k2p = (64 - k2) & 63;
            float2 Zk = Z[0][k2];
            float2 Zr = Z[0][k2p];
            float2 Zrc = make_float2(Zr.x, -Zr.y);
            float2 D = make_float2(0.5f*(Zk.x + Zrc.x), 0.5f*(Zk.y + Zrc.y));
            float2 df = make_float2(Zk.x - Zrc.x, Zk.y - Zrc.y);
            float2 I = make_float2(0.5f*df.y, -0.5f*df.x);
            int k = 512*k2;
            int jjb = (k <= NSAMP - k) ? k : NSAMP - k;
            float fv = 0.0f;
            if (jjb < NSAMP/2) {
                float pos = (jjb + 0.5f) * (1.0f/1024.0f) - 0.5f;
                pos = fminf(fmaxf(pos, 0.0f), 15.0f);
                int i0 = (int)pos;
                float w = pos - (float)i0;
                int i1 = (i0 + 1 > 15) ? 15 : i0 + 1;
                fv = fs[i0]*(1.0f - w) + fs[i1]*w;
            }
            float2 spec = cmul(D, I);
            float gs = fv * SCALE;
            Z[0][k2]  = make_float2( spec.x*gs,  spec.y*gs);
            Z[0][k2p] = make_float2( spec.x*gs, -spec.y*gs);
        }
        if (l < 32) {             // col 256: k2 <-> 63-k2, k2 in [0,32)
            int k2 = l, k2p = 63 - k2;
            float2 Zk = Z[4][k2];
            float2 Zr = Z[4][k2p];
            float2 Zrc = make_float2(Zr.x, -Zr.y);
            float2 D = make_float2(0.5f*(Zk.x + Zrc.x), 0.5f*(Zk.y + Zrc.y));
            float2 df = make_float2(Zk.x - Zrc.x, Zk.y - Zrc.y);
            float2 I = make_float2(0.5f*df.y, -0.5f*df.x);
            int k = 256 + 512*k2;
            int jjb = (k <= NSAMP - k) ? k : NSAMP - k;
            float fv = 0.0f;
            {
                float pos = (jjb + 0.5f) * (1.0f/1024.0f) - 0.5f;
                pos = fminf(fmaxf(pos, 0.0f), 15.0f);
                int i0 = (int)pos;
                float w = pos - (float)i0;
                int i1 = (i0 + 1 > 15) ? 15 : i0 + 1;
                fv = fs[i0]*(1.0f - w) + fs[i1]*w;
            }
            float2 spec = cmul(D, I);
            float gs = fv * SCALE;
            Z[4][k2]  = make_float2( spec.x*gs,  spec.y*gs);
            Z[4][k2p] = make_float2( spec.x*gs, -spec.y*gs);
        }
    }
    __syncthreads();

    // ---- step 3: inverse 64-pt FFT (sign=+1) over k2, column mycol ----
#pragma unroll
    for (int q = 0; q < 8; ++q) v[q] = Z[cc][jj + 8*q];
    bfly8(v, 1.0f, X);
#pragma unroll
    for (int r = 0; r < 8; ++r) buf[phi(cc*64 + jj*8 + r)] = X[r];
    __syncthreads();
#pragma unroll
    for (int q = 0; q < 8; ++q) v[q] = buf[phi(cc*64 + jj + 8*q)];
    twiddle_q(v, TWO_PI * (float)jj * (1.0f/64.0f));
    bfly8(v, 1.0f, X);

    // T[mycol][n2], n2 = jj+8r; twiddle w_N^{+n2*mycol}; store H[n2*512+mycol]
    float2* hp = H + s * NSAMP + mycol;
#pragma unroll
    for (int r = 0; r < 8; ++r) {
        int n2 = jj + 8*r;
        int pr = (n2 * mycol) & (NSAMP - 1);
        float sa, ca; __sincosf(TWO_PI * (float)pr * (1.0f/32768.0f), &sa, &ca);
        hp[n2*512] = cmul(X[r], make_float2(ca, sa));
    }
}

// ---------------------------------------------------------------------------
// Kernel 4: final inverse 512-pt FFT over k1 per (s, n2); input H[n2*512+k1]
// coalesced; NO extra twiddle (already applied in mega); store real part:
// out[s][64*n1 + n2], n1 = j + 64r.
__global__ void fft512_out_kernel(const float2* __restrict__ H,
                                  float* __restrict__ out) {
    const int j  = threadIdx.x;          // 64
    const int s  = blockIdx.x >> 6;
    const int n2 = blockIdx.x & 63;
    __shared__ float2 buf[2][576];
    const float sign = 1.0f;

    const float2* sp = H + s * NSAMP;
    float2 v[8], X[8];
#pragma unroll
    for (int q = 0; q < 8; ++q) v[q] = sp[n2*512 + j + 64*q];

    bfly8(v, sign, X);
#pragma unroll
    for (int r = 0; r < 8; ++r) buf[0][phi(8*j + r)] = X[r];
    __syncthreads();
#pragma unroll
    for (int q = 0; q < 8; ++q) v[q] = buf[0][phi(j + 64*q)];
    int jm = j & 7;
    twiddle_q(v, sign * TWO_PI * (float)jm * (1.0f/64.0f));
    bfly8(v, sign, X);
#pragma unroll
    for (int r = 0; r < 8; ++r) buf[1][phi(((j>>3)<<6) + jm + (r<<3))] = X[r];
    __syncthreads();
#pragma unroll
    for (int q = 0; q < 8; ++q) v[q] = buf[1][phi(j + 64*q)];
    twiddle_q(v, sign * TWO_PI * (float)j * (1.0f/512.0f));
    bfly8(v, sign, X);

    float* op = out + s * NSAMP + n2;
#pragma unroll
    for (int r = 0; r < 8; ++r) op[64*j + 4096*r] = X[r].x;
}

// ---------------------------------------------------------------------------
extern "C" void kernel_launch(void* const* d_in, const int* in_sizes, int n_in,
                              void* d_out, int out_size, void* d_ws, size_t ws_size,
                              hipStream_t stream) {
    const float* impulse = (const float*)d_in[0];   // [8,128]
    const float* dsel    = (const float*)d_in[1];   // [8,512,16]
    const float* damping = (const float*)d_in[2];   // [8,1]
    const float* filt    = (const float*)d_in[3];   // [8,16]
    const float* noise   = (const float*)d_in[4];   // [8,1,32768]
    // d_in[5] (delays, 64 MB): pure structure delays[i,n] = ((i+1) | n) — never read.
    float* out = (float*)d_out;                     // [8,32768]

    float2* A = (float2*)d_ws;                      // 2 MB
    float2* B = A + BATCH * NSAMP;                  // 2 MB

    // NOTE (R5 lesson): do NOT fuse via hipLaunchCooperativeKernel —
    // grid.sync() on gfx950 costs ~75 µs/barrier. Stream-ordered kernel
    // boundaries ARE the cheap global barrier here.
    build_kernel    <<<dim3(512), dim3(64), 0, stream>>>(impulse, dsel, damping, noise, A);
    fft512_fwd_kernel<<<dim3(512), dim3(64), 0, stream>>>(A, B);
    mega_kernel     <<<dim3(512), dim3(64), 0, stream>>>(B, A, filt);
    fft512_out_kernel<<<dim3(512), dim3(64), 0, stream>>>(A, out);
}